// Round 13
// baseline (244.060 us; speedup 1.0000x reference)
//
#include <hip/hip_runtime.h>

#define B_SZ 4096
#define T_SZ 64
#define F_SZ 512
#define H_SZ 64
#define BR 8                    // 512 blocks, 2 blocks/CU
#define WIH_ELEMS (256 * 512)

typedef _Float16 f16x4 __attribute__((ext_vector_type(4)));
typedef _Float16 f16x8 __attribute__((ext_vector_type(8)));
typedef float f32x4 __attribute__((ext_vector_type(4)));

__device__ __forceinline__ float fast_rcp(float x) { return __builtin_amdgcn_rcpf(x); }
__device__ __forceinline__ float sigm(float x) { return fast_rcp(1.0f + __expf(-x)); }
__device__ __forceinline__ float tanh_f(float x) {
  x = fminf(15.0f, fmaxf(-15.0f, x));
  float e = __expf(2.0f * x);
  return (e - 1.0f) * fast_rcp(e + 1.0f);
}

__global__ void transcode_f16(const float* __restrict__ Wih, const float* __restrict__ Whh,
                              _Float16* __restrict__ ws) {
  const int i4 = (blockIdx.x * 256 + threadIdx.x) * 4;
  if (i4 < WIH_ELEMS) {
    float4 v = *(const float4*)(Wih + i4);
    ws[i4] = (_Float16)v.x; ws[i4+1] = (_Float16)v.y; ws[i4+2] = (_Float16)v.z; ws[i4+3] = (_Float16)v.w;
  } else {
    const int j4 = i4 - WIH_ELEMS;
    float4 v = *(const float4*)(Whh + j4);
    _Float16* w2 = ws + WIH_ELEMS;
    w2[j4] = (_Float16)v.x; w2[j4+1] = (_Float16)v.y; w2[j4+2] = (_Float16)v.z; w2[j4+3] = (_Float16)v.w;
  }
}

// Fused LSTM: merged scan (R11) + 2-deep x prefetch (R12) + 512B DRAM segments (new).
// Staging unit tau (0..63): chunk cc=tau>>3, kq=(tau&7)>>1, mhalf=tau&1.
// Unit = 32 m-rows x 128 k fp32: each (b,t) row contributes one CONTIGUOUS 512B segment
// (vs 256B in R12) -> double the DRAM burst per page visit.
// kq outer / mhalf inner: B(kq)=bfr[4][4] loaded once per kq (iterA only), reused by both
// mhalf units -> B L2 traffic unchanged. Waits: iterA MFMA B-wait = vmcnt(4) (retires
// x(tau+1), 1 iter old; x(tau+2) stays); iterB stageW wait = vmcnt(4) (same property).
__global__ __launch_bounds__(256, 2)
void lstm_fused(const float* __restrict__ x, const _Float16* __restrict__ ws,
                const float* __restrict__ bih, const float* __restrict__ bhh,
                const float* __restrict__ Wfc, const float* __restrict__ bfc,
                float* __restrict__ out)
{
  __shared__ __align__(16) _Float16 Ast[2][32 * 128];  // 2 x 8KB fp16 units, granule-swizzled
  __shared__ __align__(16) _Float16 xgb[8][8][256];    // 32KB: [step][brow][u*4+g]
  __shared__ __align__(16) _Float16 hbuf[2][8][72];
  __shared__ float cb[8][64];
  __shared__ float h32[8][64];

  const int tid  = threadIdx.x;
  const int wv   = tid >> 6;
  const int lane = tid & 63;
  const int ln   = lane & 15;
  const int kg   = lane >> 4;
  const int br0  = blockIdx.x * BR;
  const int u    = wv * 16 + ln;

  const _Float16* Wihh = ws;
  const _Float16* Whhh = ws + WIH_ELEMS;

  for (int i = tid; i < 2 * 8 * 72; i += 256) (&hbuf[0][0][0])[i] = (_Float16)0.0f;
  for (int i = tid; i < 8 * 64; i += 256) (&cb[0][0])[i] = 0.0f;

  f16x8 whhf[4][2];
  #pragma unroll
  for (int g = 0; g < 4; ++g)
    #pragma unroll
    for (int k2 = 0; k2 < 2; ++k2)
      whhf[g][k2] = *(const f16x8*)(Whhh + (size_t)((g * 4 + wv) * 16 + ln) * H_SZ
                                         + kg * 8 + k2 * 32);
  float bsum[4];
  #pragma unroll
  for (int g = 0; g < 4; ++g) bsum[g] = bih[g * 64 + u] + bhh[g * 64 + u];

  // x load for unit t2: wave wv covers local rows wv*8..wv*8+8; instr j = rows {+2j,+2j+1};
  // lane l -> row += (l>>5), k-chunk (l&31)*4 floats (512B contiguous per row).
  auto loadX = [&](float4 (&p)[4], int t2) {
    const int tt = t2 < 64 ? t2 : 63;          // tail clamp (L2-hot re-read, dead writes)
    const int c2 = tt >> 3, kq = (tt & 7) >> 1, mh = tt & 1;
    #pragma unroll
    for (int j = 0; j < 4; ++j) {
      const int lr = wv * 8 + 2 * j + (lane >> 5);      // 0..31
      const float* sp = x + (size_t)(br0 + (lr & 7)) * (T_SZ * F_SZ)
                          + (size_t)(c2 * 8 + mh * 4 + (lr >> 3)) * F_SZ
                          + kq * 128 + (lane & 31) * 4;
      p[j] = *(const float4*)sp;
    }
  };
  // cvt + swizzled LDS write: granule g16 = (l&31)>>1, phys = g16 ^ (lr&7), half = (l&31)&1
  auto stageW = [&](const float4 (&p)[4], int buf) {
    #pragma unroll
    for (int j = 0; j < 4; ++j) {
      const int lr = wv * 8 + 2 * j + (lane >> 5);
      const int p31 = lane & 31;
      const int pg  = (p31 >> 1) ^ (lr & 7);
      f16x4 h = {(_Float16)p[j].x, (_Float16)p[j].y, (_Float16)p[j].z, (_Float16)p[j].w};
      *(f16x4*)&Ast[buf][lr * 128 + pg * 8 + (p31 & 1) * 4] = h;
    }
  };
  // Full-kq B fragments: 16 x f16x8 (64 VGPR), loaded once per kq (iterA only)
  auto loadB = [&](f16x8 (&b)[4][4], int kq) {
    #pragma unroll
    for (int g = 0; g < 4; ++g)
      #pragma unroll
      for (int ks = 0; ks < 4; ++ks)
        b[g][ks] = *(const f16x8*)(Wihh + (size_t)((g * 4 + wv) * 16 + ln) * F_SZ
                                        + kq * 128 + ks * 32 + kg * 8);
  };

  f32x4 acc[4][4];
  f16x8 bfr[4][4];

  // consume unit (mh compile-time): 32 MFMA into acc[mh*2+tt][g]
  auto consume0 = [&](int buf) {
    #pragma unroll
    for (int ks = 0; ks < 4; ++ks)
      #pragma unroll
      for (int tt = 0; tt < 2; ++tt) {
        const int lr = tt * 16 + ln;
        const int phys = (ks * 4 + kg) ^ (ln & 7);
        f16x8 af = *(const f16x8*)&Ast[buf][lr * 128 + phys * 8];
        #pragma unroll
        for (int g = 0; g < 4; ++g)
          acc[tt][g] = __builtin_amdgcn_mfma_f32_16x16x32_f16(af, bfr[g][ks], acc[tt][g], 0, 0, 0);
      }
  };
  auto consume1 = [&](int buf) {
    #pragma unroll
    for (int ks = 0; ks < 4; ++ks)
      #pragma unroll
      for (int tt = 0; tt < 2; ++tt) {
        const int lr = tt * 16 + ln;
        const int phys = (ks * 4 + kg) ^ (ln & 7);
        f16x8 af = *(const f16x8*)&Ast[buf][lr * 128 + phys * 8];
        #pragma unroll
        for (int g = 0; g < 4; ++g)
          acc[2 + tt][g] = __builtin_amdgcn_mfma_f32_16x16x32_f16(af, bfr[g][ks], acc[2 + tt][g], 0, 0, 0);
      }
  };

  auto scanStep = [&](int st) {
    const int sl = st & 7, half = sl & 1;
    f16x8 ah0 = (f16x8){0, 0, 0, 0, 0, 0, 0, 0};
    f16x8 ah1 = (f16x8){0, 0, 0, 0, 0, 0, 0, 0};
    if ((ln >> 3) == half) {
      const _Float16* hr = &hbuf[st & 1][ln & 7][0];
      ah0 = *(const f16x8*)(hr + kg * 8);
      ah1 = *(const f16x8*)(hr + kg * 8 + 32);
    }
    const bool val = (kg >> 1) == half;
    f32x4 gf[4];
    if (val) {
      #pragma unroll
      for (int r = 0; r < 4; ++r) {
        f16x4 xv = *(const f16x4*)&xgb[sl][(kg & 1) * 4 + r][u * 4];
        gf[0][r] = (float)xv[0]; gf[1][r] = (float)xv[1];
        gf[2][r] = (float)xv[2]; gf[3][r] = (float)xv[3];
      }
    } else {
      #pragma unroll
      for (int g = 0; g < 4; ++g) gf[g] = (f32x4){0.0f, 0.0f, 0.0f, 0.0f};
    }
    #pragma unroll
    for (int g = 0; g < 4; ++g) {
      gf[g] = __builtin_amdgcn_mfma_f32_16x16x32_f16(ah0, whhf[g][0], gf[g], 0, 0, 0);
      gf[g] = __builtin_amdgcn_mfma_f32_16x16x32_f16(ah1, whhf[g][1], gf[g], 0, 0, 0);
    }
    if (val) {
      const int b0 = (kg & 1) * 4;
      #pragma unroll
      for (int r = 0; r < 4; ++r) {
        const float iv = sigm(gf[0][r] + bsum[0]);
        const float fv = sigm(gf[1][r] + bsum[1]);
        const float gv = tanh_f(gf[2][r] + bsum[2]);
        const float ov = sigm(gf[3][r] + bsum[3]);
        const float cn = fv * cb[b0 + r][u] + iv * gv;
        cb[b0 + r][u] = cn;
        const float hn = ov * tanh_f(cn);
        hbuf[(st + 1) & 1][b0 + r][u] = (_Float16)hn;
        if (st == T_SZ - 1) h32[b0 + r][u] = hn;
      }
    }
  };

  auto handoff = [&]() {
    #pragma unroll
    for (int mt = 0; mt < 4; ++mt) {
      const int sl2  = mt * 2 + (kg >> 1);
      const int brow = (kg & 1) * 4;
      #pragma unroll
      for (int r = 0; r < 4; ++r) {
        f16x4 h4 = {(_Float16)acc[mt][0][r], (_Float16)acc[mt][1][r],
                    (_Float16)acc[mt][2][r], (_Float16)acc[mt][3][r]};
        *(f16x4*)&xgb[sl2][brow + r][u * 4] = h4;
      }
    }
    asm volatile("s_waitcnt lgkmcnt(0)" ::: "memory");
    __builtin_amdgcn_s_barrier();
    #pragma unroll
    for (int mt = 0; mt < 4; ++mt)
      #pragma unroll
      for (int g = 0; g < 4; ++g) acc[mt][g] = (f32x4){0.0f, 0.0f, 0.0f, 0.0f};
  };

  float4 xpA[4], xpB[4];

// ITER(tau): SRC = x(tau+1) regs (issued 1 iter ago), DST <- x(tau+2).
// Even tau (mhalf0): loadB(kq) here; odd tau reuses bfr.
#define ITER(tau, SRC, DST)                                                    \
  do {                                                                         \
    if (((tau) & 1) == 0) loadB(bfr, ((tau) & 7) >> 1);                        \
    loadX(DST, (tau) + 2);                                                     \
    __builtin_amdgcn_sched_barrier(0);                                         \
    if (((tau) & 1) == 0) consume0((tau) & 1); else consume1((tau) & 1);       \
    if ((tau) >= 8) scanStep((tau) - 8);                                       \
    __builtin_amdgcn_sched_barrier(0);                                         \
    stageW(SRC, ((tau) + 1) & 1);                                              \
    asm volatile("s_waitcnt lgkmcnt(0)" ::: "memory");                         \
    __builtin_amdgcn_s_barrier();                                              \
    if (((tau) & 7) == 7) handoff();                                           \
  } while (0)

  // Prologue: stage unit 0; xpA <- x(1).
  loadX(xpA, 0);
  stageW(xpA, 0);
  loadX(xpA, 1);
  __syncthreads();   // zeros + unit 0 visible (one-time full drain)

  #pragma unroll
  for (int mt = 0; mt < 4; ++mt)
    #pragma unroll
    for (int g = 0; g < 4; ++g) acc[mt][g] = (f32x4){0.0f, 0.0f, 0.0f, 0.0f};

  for (int p = 0; p < 32; ++p) {
    ITER(2 * p,     xpA, xpB);
    ITER(2 * p + 1, xpB, xpA);
  }
#undef ITER

  // Epilogue: last chunk's 8 scan steps.
  for (int s2 = 56; s2 < 64; ++s2) {
    scanStep(s2);
    asm volatile("s_waitcnt lgkmcnt(0)" ::: "memory");
    __builtin_amdgcn_s_barrier();
  }

  __syncthreads();
  if (tid < 16) {
    const int r = tid >> 1, j = tid & 1;
    float a = bfc[j];
    #pragma unroll
    for (int uu = 0; uu < 64; ++uu) a += h32[r][uu] * Wfc[j * 64 + uu];
    out[(size_t)(br0 + r) * 2 + j] = a;
  }
}

extern "C" void kernel_launch(void* const* d_in, const int* in_sizes, int n_in,
                              void* d_out, int out_size, void* d_ws, size_t ws_size,
                              hipStream_t stream) {
  const float* x   = (const float*)d_in[0];
  const float* Wih = (const float*)d_in[1];
  const float* Whh = (const float*)d_in[2];
  const float* bih = (const float*)d_in[3];
  const float* bhh = (const float*)d_in[4];
  const float* Wfc = (const float*)d_in[5];
  const float* bfc = (const float*)d_in[6];
  float* out = (float*)d_out;
  _Float16* ws = (_Float16*)d_ws;   // 272 KB used

  transcode_f16<<<dim3(144), dim3(256), 0, stream>>>(Wih, Whh, ws);
  lstm_fused<<<dim3(B_SZ / BR), dim3(256), 0, stream>>>(x, ws, bih, bhh, Wfc, bfc, out);
}